// Round 1
// baseline (284.666 us; speedup 1.0000x reference)
//
#include <hip/hip_runtime.h>

// Thumbnail-L1 loss:
//   thumb = 128x128 box-mean of each image; loss = mean_b( sum_cells |fake_t - real_t| )
// Since abs is applied AFTER the per-cell mean, each cell needs only the SIGNED
// sum of (fake - real) over its 16384 pixels. One workgroup per cell.
//
// Geometry: B=32, C=1, H=W=1024, K=128 -> 8x8=64 cells/sample, 2048 cells total.
// Each cell: 128 rows x 128 cols; row segment = 128 floats = 32 float4.
// 256 threads: lane group of 32 covers one row segment (512 B contiguous),
// 8 rows per pass, 16 passes.

__global__ __launch_bounds__(256) void thumb_l1_kernel(
    const float* __restrict__ fake,
    const float* __restrict__ real,
    float* __restrict__ out)
{
    const int bid = blockIdx.x;   // 0..2047 = cell id
    const int tid = threadIdx.x;  // 0..255

    const int b  = bid >> 6;      // sample
    const int ci = bid & 63;      // cell within sample
    const int cy = ci >> 3;
    const int cx = ci & 7;

    // base element offset of this cell; multiple of 128 floats -> 16B aligned
    const size_t base = (size_t)b * (1024u * 1024u)
                      + (size_t)cy * (128u * 1024u)
                      + (size_t)cx * 128u;

    const float4* __restrict__ f4 = (const float4*)(fake + base);
    const float4* __restrict__ r4 = (const float4*)(real + base);

    const int row0 = tid >> 5;    // 0..7
    const int c4   = tid & 31;    // 0..31 (float4 column within cell row)

    float acc = 0.0f;
#pragma unroll
    for (int p = 0; p < 16; ++p) {
        const int row = (p << 3) + row0;              // 0..127
        const size_t idx = (size_t)row * 256 + c4;    // row stride = 1024/4 float4
        const float4 f = f4[idx];
        const float4 r = r4[idx];
        acc += (f.x - r.x) + (f.y - r.y) + (f.z - r.z) + (f.w - r.w);
    }

    // wave (64-lane) butterfly reduce
    #pragma unroll
    for (int off = 32; off > 0; off >>= 1)
        acc += __shfl_down(acc, off, 64);

    __shared__ float wsum[4];
    const int wave = tid >> 6;
    if ((tid & 63) == 0) wsum[wave] = acc;
    __syncthreads();

    if (tid == 0) {
        const float s = wsum[0] + wsum[1] + wsum[2] + wsum[3];
        // |cell mean| contribution: /16384 (box mean) /32 (batch mean)
        atomicAdd(out, fabsf(s) * (1.0f / (16384.0f * 32.0f)));
    }
}

extern "C" void kernel_launch(void* const* d_in, const int* in_sizes, int n_in,
                              void* d_out, int out_size, void* d_ws, size_t ws_size,
                              hipStream_t stream) {
    const float* fake = (const float*)d_in[0];
    const float* real = (const float*)d_in[1];
    float* out = (float*)d_out;

    // harness poisons d_out to 0xAA before each timed launch; we accumulate via
    // atomics so zero it on-stream (graph-capture safe)
    hipMemsetAsync(out, 0, sizeof(float), stream);

    thumb_l1_kernel<<<2048, 256, 0, stream>>>(fake, real, out);
}

// Round 2
// 278.859 us; speedup vs baseline: 1.0208x; 1.0208x over previous
//
#include <hip/hip_runtime.h>

// Thumbnail-L1 loss, two-stage streaming reduction.
//
// abs() applies AFTER the 128x128 box mean, so each cell needs only the SIGNED
// sum of (fake - real) over its 16384 pixels.
//
// Stage 1: pure sequential streaming. Grid = 32768 image rows / 16 rows per
// block = 2048 blocks. A block's 256 threads read one 4 KiB row per iteration
// (thread t owns float4 #t of the row -> fully contiguous, coalesced 16B/lane).
// Thread t's 4 columns always fall in cell column cx = t>>5, so each thread
// accumulates one signed partial; a width-32 shuffle reduce yields 8 partials
// per block (one per cx), stored without atomics:
//   partial[bid*8 + cx], bid = (b*8 + cy)*8 + g   (g = 16-row group within cell row)
//
// Stage 2: one block sums the 8 g-partials per cell, takes abs, scales by
// 1/(16384*32), reduces 2048 cells, writes out[0]. Deterministic; no memsets.

#define ROWS_PER_BLOCK 16
#define N_STAGE1_BLOCKS 2048   // 32 * 1024 / 16

__global__ __launch_bounds__(256) void thumb_stage1(
    const float* __restrict__ fake,
    const float* __restrict__ real,
    float* __restrict__ partial)
{
    const int bid = blockIdx.x;    // row-group id, 0..2047
    const int tid = threadIdx.x;   // 0..255

    // each image row = 1024 floats = 256 float4; block starts at row bid*16
    const size_t base = (size_t)bid * ROWS_PER_BLOCK * 256 + tid;
    const float4* __restrict__ f4 = (const float4*)fake + base;
    const float4* __restrict__ r4 = (const float4*)real + base;

    float acc = 0.0f;
#pragma unroll 4
    for (int r = 0; r < ROWS_PER_BLOCK; ++r) {
        const float4 f = f4[(size_t)r * 256];
        const float4 g = r4[(size_t)r * 256];
        acc += (f.x - g.x) + (f.y - g.y) + (f.z - g.z) + (f.w - g.w);
    }

    // reduce within each 32-lane group (all lanes share cx = tid>>5)
#pragma unroll
    for (int off = 16; off > 0; off >>= 1)
        acc += __shfl_down(acc, off, 32);

    if ((tid & 31) == 0)
        partial[(size_t)bid * 8 + (tid >> 5)] = acc;
}

__global__ __launch_bounds__(256) void thumb_stage2(
    const float* __restrict__ partial,
    float* __restrict__ out)
{
    const int tid = threadIdx.x;

    float acc = 0.0f;
    // 2048 cells; cell c = b*64 + cy*8 + cx -> partials at (c>>3)*64 + g*8 + (c&7)
    for (int c = tid; c < 2048; c += 256) {
        const int base = (c >> 3) * 64 + (c & 7);
        float s = 0.0f;
#pragma unroll
        for (int g = 0; g < 8; ++g)
            s += partial[base + g * 8];
        acc += fabsf(s);
    }

    // full-block reduce (4 waves)
#pragma unroll
    for (int off = 32; off > 0; off >>= 1)
        acc += __shfl_down(acc, off, 64);

    __shared__ float wsum[4];
    if ((tid & 63) == 0) wsum[tid >> 6] = acc;
    __syncthreads();

    if (tid == 0)
        out[0] = (wsum[0] + wsum[1] + wsum[2] + wsum[3]) * (1.0f / (16384.0f * 32.0f));
}

extern "C" void kernel_launch(void* const* d_in, const int* in_sizes, int n_in,
                              void* d_out, int out_size, void* d_ws, size_t ws_size,
                              hipStream_t stream) {
    const float* fake = (const float*)d_in[0];
    const float* real = (const float*)d_in[1];
    float* out = (float*)d_out;
    float* partial = (float*)d_ws;   // 2048*8 floats = 64 KiB

    thumb_stage1<<<N_STAGE1_BLOCKS, 256, 0, stream>>>(fake, real, partial);
    thumb_stage2<<<1, 256, 0, stream>>>(partial, out);
}

// Round 3
// 278.383 us; speedup vs baseline: 1.0226x; 1.0017x over previous
//
#include <hip/hip_runtime.h>

// Thumbnail-L1 loss, two-stage streaming reduction. R2: MLP-deepened stage 1.
//
// abs() applies AFTER the 128x128 box mean, so each cell needs only the SIGNED
// sum of (fake - real) over its 16384 pixels.
//
// Stage 1: 1024 blocks x 256 threads; each block handles 2 row-groups of 16
// image rows (grid-stride), so waves live 2x longer than R1 and dispatch
// overhead halves. Per row-group, a thread reads 16 float4 from each input as
// two batches of 16 INDEPENDENT loads held in registers (software-pipeline
// friendly, ~16 KiB in flight per wave) with two accumulator chains.
// Thread t's float4 of a row falls in cell column cx = t>>5 for every row, so
// one signed partial per thread; width-32 shuffle reduce -> 8 partials per
// row-group, stored deterministically (no atomics):
//   partial[rg*8 + cx],  rg = (b*8 + cy)*8 + g
//
// Stage 2: one block sums the 8 g-partials per cell, abs, scale 1/(16384*32),
// reduces 2048 cells, writes out[0]. Deterministic; no memsets needed.

#define ROWS_PER_GROUP 16
#define N_GROUPS 2048     // 32*1024 rows / 16
#define S1_BLOCKS 1024

__global__ __launch_bounds__(256) void thumb_stage1(
    const float* __restrict__ fake,
    const float* __restrict__ real,
    float* __restrict__ partial)
{
    const int tid = threadIdx.x;   // 0..255

    for (int rg = blockIdx.x; rg < N_GROUPS; rg += S1_BLOCKS) {
        // row rg*16; each row = 256 float4; thread t owns float4 #t of the row
        const size_t base = (size_t)rg * ROWS_PER_GROUP * 256 + tid;
        const float4* __restrict__ f4 = (const float4*)fake + base;
        const float4* __restrict__ r4 = (const float4*)real + base;

        float acc0 = 0.0f, acc1 = 0.0f;
#pragma unroll
        for (int r = 0; r < ROWS_PER_GROUP; r += 8) {
            float4 f[8], g[8];
#pragma unroll
            for (int j = 0; j < 8; ++j)
                f[j] = f4[(size_t)(r + j) * 256];
#pragma unroll
            for (int j = 0; j < 8; ++j)
                g[j] = r4[(size_t)(r + j) * 256];
#pragma unroll
            for (int j = 0; j < 8; ++j) {
                acc0 += (f[j].x - g[j].x) + (f[j].y - g[j].y);
                acc1 += (f[j].z - g[j].z) + (f[j].w - g[j].w);
            }
        }

        float acc = acc0 + acc1;
        // reduce within each 32-lane group (all lanes share cx = tid>>5)
#pragma unroll
        for (int off = 16; off > 0; off >>= 1)
            acc += __shfl_down(acc, off, 32);

        if ((tid & 31) == 0)
            partial[(size_t)rg * 8 + (tid >> 5)] = acc;
    }
}

__global__ __launch_bounds__(256) void thumb_stage2(
    const float* __restrict__ partial,
    float* __restrict__ out)
{
    const int tid = threadIdx.x;

    float acc = 0.0f;
    // cell c = b*64 + cy*8 + cx -> partials at (c>>3)*64 + g*8 + (c&7)
    for (int c = tid; c < 2048; c += 256) {
        const int base = (c >> 3) * 64 + (c & 7);
        float s = 0.0f;
#pragma unroll
        for (int g = 0; g < 8; ++g)
            s += partial[base + g * 8];
        acc += fabsf(s);
    }

    // full-block reduce (4 waves)
#pragma unroll
    for (int off = 32; off > 0; off >>= 1)
        acc += __shfl_down(acc, off, 64);

    __shared__ float wsum[4];
    if ((tid & 63) == 0) wsum[tid >> 6] = acc;
    __syncthreads();

    if (tid == 0)
        out[0] = (wsum[0] + wsum[1] + wsum[2] + wsum[3]) * (1.0f / (16384.0f * 32.0f));
}

extern "C" void kernel_launch(void* const* d_in, const int* in_sizes, int n_in,
                              void* d_out, int out_size, void* d_ws, size_t ws_size,
                              hipStream_t stream) {
    const float* fake = (const float*)d_in[0];
    const float* real = (const float*)d_in[1];
    float* out = (float*)d_out;
    float* partial = (float*)d_ws;   // 2048*8 floats = 64 KiB

    thumb_stage1<<<S1_BLOCKS, 256, 0, stream>>>(fake, real, partial);
    thumb_stage2<<<1, 256, 0, stream>>>(partial, out);
}